// Round 18
// baseline (1710.313 us; speedup 1.0000x reference)
//
#include <hip/hip_runtime.h>
#include <hip/hip_bf16.h>
#include <cmath>

#define NN 25600   // nodes
#define NE 307200  // edges
#define NB 256     // graphs
#define HD 256     // hidden

typedef __attribute__((ext_vector_type(8))) short short8;
typedef __attribute__((ext_vector_type(4))) float f32x4;
typedef __attribute__((ext_vector_type(2))) float f32x2;

// ---------- math helpers ----------
__device__ __forceinline__ float ntn_f(float v, float pos, float neg) {
  if (isnan(v)) return 0.f;
  if (isinf(v)) return v > 0.f ? pos : neg;
  return v;
}
__device__ __forceinline__ float ntn_def(float v) {
  if (isnan(v)) return 0.f;
  if (isinf(v)) return v > 0.f ? 3.4028234663852886e38f : -3.4028234663852886e38f;
  return v;
}
__device__ __forceinline__ float sigmoid_f(float x) { return 1.f / (1.f + __expf(-x)); }
__device__ __forceinline__ float silu_f(float x) { return x * sigmoid_f(x); }
__device__ __forceinline__ float softplus_f(float x) {
  return fmaxf(x, 0.f) + __logf(1.f + __expf(-fabsf(x)));
}
__device__ __forceinline__ unsigned short f2bf(float f) {  // RNE f32->bf16
  unsigned int u = __float_as_uint(f);
  u += 0x7fffu + ((u >> 16) & 1u);
  return (unsigned short)(u >> 16);
}
__device__ __forceinline__ float bfu(unsigned short u) {  // bf16 (as u16) -> f32
  return __uint_as_float((unsigned int)u << 16);
}

template <int NW>
__device__ __forceinline__ float blockSum(float v, float* sred) {
  int lane = threadIdx.x & 63, w = threadIdx.x >> 6;
#pragma unroll
  for (int o = 32; o; o >>= 1) v += __shfl_xor(v, o);
  __syncthreads();
  if (lane == 0) sred[w] = v;
  __syncthreads();
  float r = 0.f;
#pragma unroll
  for (int i = 0; i < NW; ++i) r += sred[i];
  return r;
}

// ---------- CSR build ----------
__global__ void k_hist(const int* __restrict__ dst, int* __restrict__ counts, int E) {
  int e = blockIdx.x * 256 + threadIdx.x;
  if (e < E) atomicAdd(&counts[dst[e]], 1);
}

__global__ __launch_bounds__(1024) void k_scan(const int* __restrict__ counts,
                                               int* __restrict__ offs, int n) {
  __shared__ int sd[1024];
  __shared__ int run;
  int tid = threadIdx.x;
  if (tid == 0) run = 0;
  __syncthreads();
  for (int base = 0; base < n; base += 1024) {
    int i = base + tid;
    int v = (i < n) ? counts[i] : 0;
    sd[tid] = v;
    __syncthreads();
    int acc = v;
    for (int off = 1; off < 1024; off <<= 1) {
      int t = (tid >= off) ? sd[tid - off] : 0;
      __syncthreads();
      acc += t;
      sd[tid] = acc;
      __syncthreads();
    }
    int r = run;
    if (i < n) offs[i] = r + acc - v;  // exclusive
    __syncthreads();
    if (tid == 1023) run = r + sd[1023];
    __syncthreads();
  }
  if (threadIdx.x == 0) offs[n] = run;
}

__global__ void k_scatter(const int* __restrict__ dst, const int* __restrict__ offs,
                          int* __restrict__ cursor, int* __restrict__ eidx, int E) {
  int e = blockIdx.x * 256 + threadIdx.x;
  if (e < E) {
    int d = dst[e];
    int p = offs[d] + atomicAdd(&cursor[d], 1);
    eidx[p] = e;
  }
}

__global__ void k_srcperm(const int* __restrict__ eidx, const int* __restrict__ srcArr,
                          int* __restrict__ srcs, int E) {
  int i = blockIdx.x * 256 + threadIdx.x;
  if (i < E) srcs[i] = srcArr[eidx[i]];
}

// ea_csr[ii][k] = edge_attr[eidx[ii]][k]  f32, CSR order -> uniform s_loads
__global__ void k_eaperm(const int* __restrict__ eidx, const float* __restrict__ ea,
                         float* __restrict__ eacsr, int E) {
  int gid = blockIdx.x * 256 + threadIdx.x;
  if (gid < E * 16) {
    int ii = gid >> 4, k = gid & 15;
    eacsr[gid] = ea[(size_t)eidx[ii] * 16 + k];
  }
}

// ---------- weight prepack: w4t[layer][c][k] bf16, c = tbl*256+j ----------
__global__ void k_pack(const float* __restrict__ conv_Wf, const float* __restrict__ conv_Ws,
                       unsigned short* __restrict__ w4t) {
  int layer = blockIdx.y;
  int gid = blockIdx.x * 256 + threadIdx.x;
  int k = gid & 255;
  int c = gid >> 8;  // 0..1023
  int j = c & 255;
  int tbl = c >> 8;
  const float* W = (tbl < 2) ? conv_Wf : conv_Ws;
  int krow = (tbl & 1) ? 256 + k : k;
  float v = W[((size_t)layer * 528 + krow) * 256 + j];
  w4t[((size_t)layer * 1024 + c) * 256 + k] = f2bf(v);
}

// edge-weight f32 prepack: wf32[layer][pr][d], pr = g*16+k (g: 0=f-gate, 1=s-gate)
// value = WgE[k][d], WgE = rows 512..527 of conv_Wg
__global__ void k_packEf(const float* __restrict__ conv_Wf, const float* __restrict__ conv_Ws,
                         float* __restrict__ wf32) {
  int layer = blockIdx.y;
  int gid = blockIdx.x * 256 + threadIdx.x;  // 32*256 = 8192 per layer
  int pr = gid >> 8, d = gid & 255;
  int g = pr >> 4, k = pr & 15;
  const float* W = g ? conv_Ws : conv_Wf;
  wf32[((size_t)layer * 32 + pr) * 256 + d] = W[((size_t)layer * 528 + 512 + k) * 256 + d];
}

// ---------- GNN input layer ----------
__global__ void k_gin(const float* __restrict__ x, const float* __restrict__ W,
                      const float* __restrict__ bias, float* __restrict__ h,
                      unsigned short* __restrict__ hbf) {
  int n = blockIdx.x, j = threadIdx.x;
  float xv[7];
#pragma unroll
  for (int k = 0; k < 7; ++k) xv[k] = ntn_f(x[n * 7 + k], 3.f, -3.f);
  float acc = bias[j];
#pragma unroll
  for (int k = 0; k < 7; ++k) acc += xv[k] * W[k * 256 + j];
  float o = silu_f(acc);
  h[(size_t)n * 256 + j] = o;
  hbf[(size_t)n * 256 + j] = f2bf(o);
}

// ---------- MFMA node GEMM: P[N,1024](bf16) = hbf @ w4t^T (+bias on dst cols) ----------
__global__ __launch_bounds__(256) void k_gemm_bf16(
    const unsigned short* __restrict__ Abf,  // [M,256] bf16 row-major
    const unsigned short* __restrict__ w4t,  // [1024,256] bf16 (col, k)
    const float* __restrict__ bf, const float* __restrict__ bs,
    unsigned short* __restrict__ Pout) {     // [M,1024] bf16
  __shared__ unsigned short As[128 * 56];
  __shared__ unsigned short Bs[128 * 56];
  int tid = threadIdx.x;
  int lane = tid & 63, w = tid >> 6;
  int wr = w >> 1, wc = w & 1;
  int m0 = blockIdx.x * 128, n0 = blockIdx.y * 128;
  int l15 = lane & 15, l4 = lane >> 4;
  f32x4 acc[4][4];
#pragma unroll
  for (int i = 0; i < 4; ++i)
#pragma unroll
    for (int j = 0; j < 4; ++j) acc[i][j] = (f32x4)0.f;
  for (int kt = 0; kt < 8; ++kt) {
    int k0 = kt * 32;
    if (kt) __syncthreads();
#pragma unroll
    for (int c = 0; c < 2; ++c) {
      int chunk = tid + c * 256;
      int row = chunk >> 2, q = chunk & 3;
      *(uint4*)&As[row * 56 + q * 8] =
          *(const uint4*)&Abf[(size_t)(m0 + row) * 256 + k0 + q * 8];
      *(uint4*)&Bs[row * 56 + q * 8] =
          *(const uint4*)&w4t[(size_t)(n0 + row) * 256 + k0 + q * 8];
    }
    __syncthreads();
    short8 a[4], b[4];
#pragma unroll
    for (int f = 0; f < 4; ++f) {
      a[f] = *(const short8*)&As[(wr * 64 + f * 16 + l15) * 56 + l4 * 8];
      b[f] = *(const short8*)&Bs[(wc * 64 + f * 16 + l15) * 56 + l4 * 8];
    }
#pragma unroll
    for (int i = 0; i < 4; ++i)
#pragma unroll
      for (int j = 0; j < 4; ++j)
        acc[i][j] = __builtin_amdgcn_mfma_f32_16x16x32_bf16(a[i], b[j], acc[i][j], 0, 0, 0);
  }
#pragma unroll
  for (int j = 0; j < 4; ++j) {
    int gcol = n0 + wc * 64 + j * 16 + l15;
    float bias = (gcol < 256) ? bf[gcol] : (gcol >= 512 && gcol < 768) ? bs[gcol - 512] : 0.f;
#pragma unroll
    for (int i = 0; i < 4; ++i) {
#pragma unroll
      for (int r = 0; r < 4; ++r) {
        int grow = m0 + wr * 64 + i * 16 + l4 * 4 + r;
        Pout[(size_t)grow * 1024 + gcol] = f2bf(acc[i][j][r] + bias);
      }
    }
  }
}

// ---------- fused edge-message + aggregate + residual + LN ----------
// FOUR WAVES PER NODE; lane owns ONE dim d = wave*64 + lane.
// r17 lesson: dot2-f16 variants are time-INVARIANT at ~288 cy/iter across all
// weight-residency schemes -> consistent with v_dot2 issuing at quarter rate
// (16 dots = 128 cy). This round: 32 full-rate f32 v_fmac (64 cy) with the
// uniform ea coefficient from SGPR (s_load) and the weight from LDS f32
// [k][256] (bank-conflict-free ds_read_b32 with constant offsets).
__global__ __launch_bounds__(256) void k_edge6(
    const float* __restrict__ h, const unsigned short* __restrict__ P,
    const float* __restrict__ eacsr,
    const int* __restrict__ srcs, const int* __restrict__ offs,
    const float* __restrict__ wf32,  // this layer: [32 pr][256 d] f32
    const float* __restrict__ lng, const float* __restrict__ lnb,
    float* __restrict__ hout, unsigned short* __restrict__ hbfout) {
  __shared__ float wldsf[32 * 256];  // 32KB
  __shared__ float sr1[4], sr2[4];
  int tid = threadIdx.x, lane = tid & 63, w = tid >> 6;
  int n = blockIdx.x;
  int d = w * 64 + lane;

  {  // stage 8192 f32 (coalesced): each thread copies 8 uint4 = 32 floats
    const float4* g = (const float4*)wf32;
    float4* l = (float4*)wldsf;
#pragma unroll
    for (int q = 0; q < 8; ++q) l[q * 256 + tid] = g[q * 256 + tid];
  }
  __syncthreads();

  float lg = lng[d], lb = lnb[d];
  const unsigned short* Pn = P + (size_t)n * 1024;
  float pfd = bfu(Pn[d]);        // dst f
  float psd = bfu(Pn[512 + d]);  // dst s
  float hn = h[(size_t)n * 256 + d];
  float acc = 0.f;
  int e0 = __builtin_amdgcn_readfirstlane(offs[n]);
  int e1 = __builtin_amdgcn_readfirstlane(offs[n + 1]);
  const unsigned short* Pf = P + 256 + d;  // single gather base

  for (int ii = e0; ii < e1; ++ii) {
    int s = srcs[ii];  // uniform -> scalar load
    size_t so = (size_t)s * 1024;
    unsigned short uf = Pf[so];        // src f gather (128B/wave contiguous)
    unsigned short us = Pf[so + 512];  // src s gather (same base, imm offset)
    const float* eaP = eacsr + ((size_t)ii << 4);  // uniform -> s_load x4
    float af = pfd, as_ = psd;
#pragma unroll
    for (int k = 0; k < 16; ++k) {
      float c = eaP[k];  // SGPR
      af = fmaf(c, wldsf[k * 256 + d], af);           // v_fmac s,v (full rate)
      as_ = fmaf(c, wldsf[(16 + k) * 256 + d], as_);
    }
    af += bfu(uf);
    as_ += bfu(us);
    acc += sigmoid_f(af) * softplus_f(as_);
  }
  float cv = hn + acc;
  float t = silu_f(cv) + hn;
  float s1 = t, s2 = t * t;
#pragma unroll
  for (int o = 32; o; o >>= 1) {
    s1 += __shfl_xor(s1, o);
    s2 += __shfl_xor(s2, o);
  }
  if (lane == 0) { sr1[w] = s1; sr2[w] = s2; }
  __syncthreads();
  float S1 = sr1[0] + sr1[1] + sr1[2] + sr1[3];
  float S2 = sr2[0] + sr2[1] + sr2[2] + sr2[3];
  float mean = S1 * (1.f / 256.f);
  float var = S2 * (1.f / 256.f) - mean * mean;
  float inv = rsqrtf(var + 1e-5f);
  float o0 = (t - mean) * inv * lg + lb;
  hout[(size_t)n * 256 + d] = o0;
  hbfout[(size_t)n * 256 + d] = f2bf(o0);
}

// ---------- pooling: batch = repeat(arange(256),100) -> contiguous segments ----------
__global__ __launch_bounds__(256) void k_pool2(const float* __restrict__ h,
                                               float* __restrict__ pooled) {
  int b = blockIdx.x, j = threadIdx.x;
  const float* hp = h + (size_t)b * 100 * 256 + j;
  float s = 0.f;
  for (int i = 0; i < 100; ++i) s += hp[(size_t)i * 256];
  pooled[b * 256 + j] = s * 0.01f;
}

__global__ void k_zgnn(const float* __restrict__ pooled,
                       const float* __restrict__ W, const float* __restrict__ bias,
                       float* __restrict__ zf) {
  int b = blockIdx.x, j = threadIdx.x;  // 192 threads
  float acc = bias[j];
  for (int k = 0; k < 256; ++k) acc += pooled[b * 256 + k] * W[k * 192 + j];
  zf[b * 384 + j] = ntn_def(acc);
}

// ---------- TDA projector ----------
__global__ __launch_bounds__(256) void k_tda(const float* __restrict__ tda,
    const float* __restrict__ W1, const float* __restrict__ b1,
    const float* __restrict__ g1, const float* __restrict__ bb1,
    const float* __restrict__ W2, const float* __restrict__ b2,
    const float* __restrict__ g2, const float* __restrict__ bb2,
    const float* __restrict__ W3, const float* __restrict__ b3, float* __restrict__ zf) {
  __shared__ float sin_[32];
  __shared__ float sa[256];
  __shared__ float sred[4];
  int b = blockIdx.x, tid = threadIdx.x;
  if (tid < 32) sin_[tid] = ntn_f(tda[b * 32 + tid], 3.f, -3.f);
  __syncthreads();
  float v = b1[tid];
#pragma unroll
  for (int k = 0; k < 32; ++k) v += sin_[k] * W1[k * 256 + tid];
  v = silu_f(v);
  float s1 = blockSum<4>(v, sred);
  float s2 = blockSum<4>(v * v, sred);
  float mean = s1 * (1.f / 256.f), var = s2 * (1.f / 256.f) - mean * mean;
  float inv = rsqrtf(var + 1e-5f);
  v = (v - mean) * inv * g1[tid] + bb1[tid];
  sa[tid] = v;
  __syncthreads();
  float v2 = b2[tid];
  for (int k = 0; k < 256; ++k) v2 += sa[k] * W2[k * 256 + tid];
  v2 = silu_f(v2);
  s1 = blockSum<4>(v2, sred);
  s2 = blockSum<4>(v2 * v2, sred);
  mean = s1 * (1.f / 256.f); var = s2 * (1.f / 256.f) - mean * mean;
  inv = rsqrtf(var + 1e-5f);
  v2 = (v2 - mean) * inv * g2[tid] + bb2[tid];
  __syncthreads();
  sa[tid] = v2;
  __syncthreads();
  if (tid < 128) {
    float o = b3[tid];
    for (int k = 0; k < 256; ++k) o += sa[k] * W3[k * 128 + tid];
    zf[b * 384 + 192 + tid] = ntn_def(o);
  }
}

// ---------- MEGNet projector ----------
__global__ __launch_bounds__(128) void k_meg(const float* __restrict__ mg,
    const float* __restrict__ W1, const float* __restrict__ b1,
    const float* __restrict__ g1, const float* __restrict__ bb1,
    const float* __restrict__ W2, const float* __restrict__ b2,
    const float* __restrict__ g2, const float* __restrict__ bb2,
    const float* __restrict__ W3, const float* __restrict__ b3, float* __restrict__ zf) {
  __shared__ float sin_[16];
  __shared__ float sa[128];
  __shared__ float sred[2];
  int b = blockIdx.x, tid = threadIdx.x;
  if (tid < 16) sin_[tid] = ntn_f(mg[b * 16 + tid], 3.f, -3.f);
  __syncthreads();
  float v = b1[tid];
#pragma unroll
  for (int k = 0; k < 16; ++k) v += sin_[k] * W1[k * 128 + tid];
  v = silu_f(v);
  float s1 = blockSum<2>(v, sred);
  float s2 = blockSum<2>(v * v, sred);
  float mean = s1 * (1.f / 128.f), var = s2 * (1.f / 128.f) - mean * mean;
  float inv = rsqrtf(var + 1e-5f);
  v = (v - mean) * inv * g1[tid] + bb1[tid];
  sa[tid] = v;
  __syncthreads();
  float v2 = b2[tid];
  for (int k = 0; k < 128; ++k) v2 += sa[k] * W2[k * 128 + tid];
  v2 = silu_f(v2);
  s1 = blockSum<2>(v2, sred);
  s2 = blockSum<2>(v2 * v2, sred);
  mean = s1 * (1.f / 128.f); var = s2 * (1.f / 128.f) - mean * mean;
  inv = rsqrtf(var + 1e-5f);
  v2 = (v2 - mean) * inv * g2[tid] + bb2[tid];
  __syncthreads();
  sa[tid] = v2;
  __syncthreads();
  if (tid < 64) {
    float o = b3[tid];
    for (int k = 0; k < 128; ++k) o += sa[k] * W3[k * 64 + tid];
    zf[b * 384 + 320 + tid] = ntn_def(o);
  }
}

// ---------- fused fusion-LN + CPPN head (fully parallel) ----------
__global__ __launch_bounds__(384) void k_cppn(const float* __restrict__ zf,
    const float* __restrict__ flng, const float* __restrict__ flnb,
    const float* __restrict__ g1W, const float* __restrict__ g1b,
    const float* __restrict__ hg, const float* __restrict__ hb,
    const float* __restrict__ g2W, const float* __restrict__ g2b,
    const float* __restrict__ g3W, const float* __restrict__ g3b,
    const float* __restrict__ plW, const float* __restrict__ plb,
    const float* __restrict__ pq1W, const float* __restrict__ pq1b,
    const float* __restrict__ pq2W, const float* __restrict__ pq2b,
    const float* __restrict__ pc1W, const float* __restrict__ pc1b,
    const float* __restrict__ pc2W, const float* __restrict__ pc2b,
    float* __restrict__ zout, float* __restrict__ y) {
  __shared__ float sz[384];
  __shared__ float sred[6];
  __shared__ float sg[48];
  __shared__ float s24[24];
  __shared__ float gates[6];
  __shared__ float lin[6];
  __shared__ float qv[6], cvv[6];
  __shared__ float mn48, iv48;
  __shared__ float prodq[1152];  // 6*192
  __shared__ float prodc[576];   // 6*96
  int b = blockIdx.x, tid = threadIdx.x;
  int lane = tid & 63, wv = tid >> 6;

  float v = zf[(size_t)b * 384 + tid];
  float s1 = blockSum<6>(v, sred);
  float s2 = blockSum<6>(v * v, sred);
  float mean = s1 * (1.f / 384.f), var = s2 * (1.f / 384.f) - mean * mean;
  float inv = rsqrtf(var + 1e-5f);
  float zv = (v - mean) * inv * flng[tid] + flnb[tid];
  sz[tid] = zv;
  zout[(size_t)b * 384 + tid] = zv;
  __syncthreads();

  {
    int j = tid >> 3, p = tid & 7;
    float a = 0.f;
    for (int d = p; d < 384; d += 8) a += sz[d] * g1W[d * 48 + j];
    a += __shfl_xor(a, 1);
    a += __shfl_xor(a, 2);
    a += __shfl_xor(a, 4);
    if (p == 0) sg[j] = silu_f(a + g1b[j]);
  }
  __syncthreads();
  if (tid < 64) {
    float x = (tid < 48) ? sg[tid] : 0.f;
    float t1 = x, t2 = x * x;
#pragma unroll
    for (int o = 32; o; o >>= 1) {
      t1 += __shfl_xor(t1, o);
      t2 += __shfl_xor(t2, o);
    }
    if (tid == 0) {
      mn48 = t1 * (1.f / 48.f);
      float vr = t2 * (1.f / 48.f) - mn48 * mn48;
      iv48 = rsqrtf(vr + 1e-5f);
    }
  }
  __syncthreads();
  if (tid < 48) sg[tid] = (sg[tid] - mn48) * iv48 * hg[tid] + hb[tid];
  __syncthreads();
  {
    int j = tid >> 4, p = tid & 15;
    int d0 = p * 3;
    float a = sg[d0] * g2W[d0 * 24 + j] + sg[d0 + 1] * g2W[(d0 + 1) * 24 + j] +
              sg[d0 + 2] * g2W[(d0 + 2) * 24 + j];
    a += __shfl_xor(a, 1);
    a += __shfl_xor(a, 2);
    a += __shfl_xor(a, 4);
    a += __shfl_xor(a, 8);
    if (p == 0) s24[j] = silu_f(a + g2b[j]);
  }
  __syncthreads();
  if (tid < 6) {
    float a = g3b[tid];
    for (int k = 0; k < 24; ++k) a += s24[k] * g3W[k * 6 + tid];
    gates[tid] = a;
  }
  __syncthreads();
  if (tid == 0) {
    float mx = gates[0];
    for (int i = 1; i < 6; ++i) mx = fmaxf(mx, gates[i]);
    float s = 0.f;
    for (int i = 0; i < 6; ++i) { gates[i] = __expf(gates[i] - mx); s += gates[i]; }
    float rs = 1.f / s;
    for (int i = 0; i < 6; ++i) gates[i] *= rs;
  }
  {
    float p = 0.f;
    for (int d = lane; d < 384; d += 64) p += sz[d] * plW[wv * 384 + d];
#pragma unroll
    for (int o = 32; o; o >>= 1) p += __shfl_xor(p, o);
    if (lane == 0) lin[wv] = p + plb[wv];
  }
  if (tid < 288) {
    int k = tid / 48, m4 = (tid % 48) * 4;
    f32x4 a = (f32x4)0.f;
    const float* Wp = pq1W + (size_t)k * 384 * 192 + m4;
    for (int d = 0; d < 384; ++d) {
      float4 w4 = *(const float4*)(Wp + (size_t)d * 192);
      float zd = sz[d];
      a.x += zd * w4.x; a.y += zd * w4.y; a.z += zd * w4.z; a.w += zd * w4.w;
    }
#pragma unroll
    for (int r = 0; r < 4; ++r) {
      int m = m4 + r;
      prodq[k * 192 + m] = silu_f(a[r] + pq1b[k * 192 + m]) * pq2W[k * 192 + m];
    }
  }
  if (tid < 144) {
    int k = tid / 24, m4 = (tid % 24) * 4;
    f32x4 a = (f32x4)0.f;
    const float* Wp = pc1W + (size_t)k * 384 * 96 + m4;
    for (int d = 0; d < 384; ++d) {
      float4 w4 = *(const float4*)(Wp + (size_t)d * 96);
      float zd = sz[d];
      a.x += zd * w4.x; a.y += zd * w4.y; a.z += zd * w4.z; a.w += zd * w4.w;
    }
#pragma unroll
    for (int r = 0; r < 4; ++r) {
      int m = m4 + r;
      float sl = silu_f(a[r] + pc1b[k * 96 + m]);
      prodc[k * 96 + m] = sl * sl * pc2W[k * 96 + m];
    }
  }
  __syncthreads();
  {
    float s = prodq[wv * 192 + lane] + prodq[wv * 192 + 64 + lane] +
              prodq[wv * 192 + 128 + lane];
#pragma unroll
    for (int o = 32; o; o >>= 1) s += __shfl_xor(s, o);
    if (lane == 0) qv[wv] = s + pq2b[wv];
    float c = prodc[wv * 96 + lane];
    float c2 = (lane < 32) ? prodc[wv * 96 + 64 + lane] : 0.f;
    float sc = c + c2;
#pragma unroll
    for (int o = 32; o; o >>= 1) sc += __shfl_xor(sc, o);
    if (lane == 0) cvv[wv] = sc + pc2b[wv];
  }
  __syncthreads();
  if (tid == 0) {
    float yy = 0.f;
    for (int k = 0; k < 6; ++k) yy += gates[k] * (lin[k] + qv[k] + cvv[k]);
    y[b] = yy;
  }
}

extern "C" void kernel_launch(void* const* d_in, const int* in_sizes, int n_in,
                              void* d_out, int out_size, void* d_ws, size_t ws_size,
                              hipStream_t stream) {
  const float* x         = (const float*)d_in[0];
  const float* edge_attr = (const float*)d_in[1];
  const float* tda       = (const float*)d_in[2];
  const float* megnet    = (const float*)d_in[3];
  const int*   edge_index= (const int*)d_in[4];
  const float* gin_W = (const float*)d_in[6];
  const float* gin_b = (const float*)d_in[7];
  const float* conv_Wf = (const float*)d_in[8];
  const float* conv_bf = (const float*)d_in[9];
  const float* conv_Ws = (const float*)d_in[10];
  const float* conv_bs = (const float*)d_in[11];
  const float* gln_g = (const float*)d_in[12];
  const float* gln_b = (const float*)d_in[13];
  const float* gout_W = (const float*)d_in[14];
  const float* gout_b = (const float*)d_in[15];
  const float* t1_W = (const float*)d_in[16];
  const float* t1_b = (const float*)d_in[17];
  const float* tln1_g = (const float*)d_in[18];
  const float* tln1_b = (const float*)d_in[19];
  const float* t2_W = (const float*)d_in[20];
  const float* t2_b = (const float*)d_in[21];
  const float* tln2_g = (const float*)d_in[22];
  const float* tln2_b = (const float*)d_in[23];
  const float* t3_W = (const float*)d_in[24];
  const float* t3_b = (const float*)d_in[25];
  const float* m1_W = (const float*)d_in[26];
  const float* m1_b = (const float*)d_in[27];
  const float* mln1_g = (const float*)d_in[28];
  const float* mln1_b = (const float*)d_in[29];
  const float* m2_W = (const float*)d_in[30];
  const float* m2_b = (const float*)d_in[31];
  const float* mln2_g = (const float*)d_in[32];
  const float* mln2_b = (const float*)d_in[33];
  const float* m3_W = (const float*)d_in[34];
  const float* m3_b = (const float*)d_in[35];
  const float* fln_g = (const float*)d_in[36];
  const float* fln_b = (const float*)d_in[37];
  const float* g1_W = (const float*)d_in[38];
  const float* g1_b = (const float*)d_in[39];
  const float* hln_g = (const float*)d_in[40];
  const float* hln_b = (const float*)d_in[41];
  const float* g2_W = (const float*)d_in[42];
  const float* g2_b = (const float*)d_in[43];
  const float* g3_W = (const float*)d_in[44];
  const float* g3_b = (const float*)d_in[45];
  const float* plin_W = (const float*)d_in[46];
  const float* plin_b = (const float*)d_in[47];
  const float* pq1_W = (const float*)d_in[48];
  const float* pq1_b = (const float*)d_in[49];
  const float* pq2_W = (const float*)d_in[50];
  const float* pq2_b = (const float*)d_in[51];
  const float* pc1_W = (const float*)d_in[52];
  const float* pc1_b = (const float*)d_in[53];
  const float* pc2_W = (const float*)d_in[54];
  const float* pc2_b = (const float*)d_in[55];

  // ---- workspace layout (~150 MB) ----
  float* ws = (float*)d_ws;
  float* hA = ws;                                        // NN*256 f32
  float* hB = hA + (size_t)NN * 256;
  float* pooled = hB + (size_t)NN * 256;                 // NB*256
  float* zf = pooled + (size_t)NB * 256;                 // NB*384
  float* eacsr = zf + (size_t)NB * 384;                  // NE*16 f32
  float* wf32 = eacsr + (size_t)NE * 16;                 // 6*32*256 f32
  unsigned short* hbfA = (unsigned short*)(wf32 + (size_t)6 * 32 * 256);  // NN*256 bf16
  unsigned short* hbfB = hbfA + (size_t)NN * 256;
  unsigned short* Pbf = hbfB + (size_t)NN * 256;         // NN*1024 bf16
  unsigned short* w4t = Pbf + (size_t)NN * 1024;         // 6*1024*256 bf16
  int* counts = (int*)(w4t + (size_t)6 * 1024 * 256);    // NN
  int* cursor = counts + NN;                             // NN
  int* offs = cursor + NN;                               // NN+1
  int* eidx = offs + NN + 1;                             // NE
  int* srcs = eidx + NE;                                 // NE

  const int* srcArr = edge_index;       // row 0 = src
  const int* dstArr = edge_index + NE;  // row 1 = dst

  hipMemsetAsync(counts, 0, (size_t)2 * NN * sizeof(int), stream);

  k_hist<<<(NE + 255) / 256, 256, 0, stream>>>(dstArr, counts, NE);
  k_scan<<<1, 1024, 0, stream>>>(counts, offs, NN);
  k_scatter<<<(NE + 255) / 256, 256, 0, stream>>>(dstArr, offs, cursor, eidx, NE);
  k_srcperm<<<(NE + 255) / 256, 256, 0, stream>>>(eidx, srcArr, srcs, NE);
  k_eaperm<<<(NE * 16 + 255) / 256, 256, 0, stream>>>(eidx, edge_attr, eacsr, NE);
  k_pack<<<dim3(1024, 6), 256, 0, stream>>>(conv_Wf, conv_Ws, w4t);
  k_packEf<<<dim3(32, 6), 256, 0, stream>>>(conv_Wf, conv_Ws, wf32);

  k_gin<<<NN, 256, 0, stream>>>(x, gin_W, gin_b, hA, hbfA);

  float* hcur = hA;          float* hnext = hB;
  unsigned short* bcur = hbfA; unsigned short* bnext = hbfB;
  for (int i = 0; i < 6; ++i) {
    k_gemm_bf16<<<dim3(NN / 128, 8), 256, 0, stream>>>(
        bcur, w4t + (size_t)i * 1024 * 256, conv_bf + i * 256, conv_bs + i * 256, Pbf);
    k_edge6<<<NN, 256, 0, stream>>>(hcur, Pbf, eacsr, srcs, offs,
                                    wf32 + (size_t)i * 32 * 256,
                                    gln_g + i * 256, gln_b + i * 256, hnext, bnext);
    float* tf = hcur; hcur = hnext; hnext = tf;
    unsigned short* tb = bcur; bcur = bnext; bnext = tb;
  }

  k_pool2<<<NB, 256, 0, stream>>>(hcur, pooled);
  k_zgnn<<<NB, 192, 0, stream>>>(pooled, gout_W, gout_b, zf);
  k_tda<<<NB, 256, 0, stream>>>(tda, t1_W, t1_b, tln1_g, tln1_b, t2_W, t2_b, tln2_g, tln2_b,
                                t3_W, t3_b, zf);
  k_meg<<<NB, 128, 0, stream>>>(megnet, m1_W, m1_b, mln1_g, mln1_b, m2_W, m2_b, mln2_g, mln2_b,
                                m3_W, m3_b, zf);

  float* yout = (float*)d_out;
  float* zout = yout + NB;
  k_cppn<<<NB, 384, 0, stream>>>(zf, fln_g, fln_b,
                                 g1_W, g1_b, hln_g, hln_b, g2_W, g2_b, g3_W, g3_b,
                                 plin_W, plin_b, pq1_W, pq1_b, pq2_W, pq2_b,
                                 pc1_W, pc1_b, pc2_W, pc2_b, zout, yout);
}

// Round 19
// 1121.728 us; speedup vs baseline: 1.5247x; 1.5247x over previous
//
#include <hip/hip_runtime.h>
#include <hip/hip_bf16.h>
#include <cmath>

#define NN 25600   // nodes
#define NE 307200  // edges
#define NB 256     // graphs
#define HD 256     // hidden

typedef __attribute__((ext_vector_type(8))) short short8;
typedef __attribute__((ext_vector_type(4))) float f32x4;
typedef __attribute__((ext_vector_type(2))) float f32x2;
typedef __attribute__((ext_vector_type(2))) _Float16 h16x2;
typedef __attribute__((ext_vector_type(2))) __fp16 fp16x2;

// ---------- math helpers ----------
__device__ __forceinline__ float ntn_f(float v, float pos, float neg) {
  if (isnan(v)) return 0.f;
  if (isinf(v)) return v > 0.f ? pos : neg;
  return v;
}
__device__ __forceinline__ float ntn_def(float v) {
  if (isnan(v)) return 0.f;
  if (isinf(v)) return v > 0.f ? 3.4028234663852886e38f : -3.4028234663852886e38f;
  return v;
}
__device__ __forceinline__ float sigmoid_f(float x) { return 1.f / (1.f + __expf(-x)); }
__device__ __forceinline__ float silu_f(float x) { return x * sigmoid_f(x); }
__device__ __forceinline__ float softplus_f(float x) {
  return fmaxf(x, 0.f) + __logf(1.f + __expf(-fabsf(x)));
}
// r18: fast sigmoid for the edge hot loop — v_rcp_f32 (1 inst) replaces the
// ~10-inst precise-div sequence. Denominator in (1,2], 1-ulp error; margin 3x.
__device__ __forceinline__ float sigmoid_fast(float x) {
  return __builtin_amdgcn_rcpf(1.f + __expf(-x));
}
__device__ __forceinline__ unsigned short f2bf(float f) {  // RNE f32->bf16
  unsigned int u = __float_as_uint(f);
  u += 0x7fffu + ((u >> 16) & 1u);
  return (unsigned short)(u >> 16);
}
__device__ __forceinline__ float bfu(unsigned short u) {  // bf16 (as u16) -> f32
  return __uint_as_float((unsigned int)u << 16);
}
__device__ __forceinline__ h16x2 u2h(unsigned int u) {
  union { unsigned int u; h16x2 h; } x; x.u = u; return x.h;
}
// cvt_pkrtz returns __fp16x2 (distinct from _Float16x2) -> union bitcast
__device__ __forceinline__ unsigned int pk2u(float a, float b) {
  union { fp16x2 p; unsigned int u; } x;
  x.p = __builtin_amdgcn_cvt_pkrtz(a, b);
  return x.u;
}
#if __has_builtin(__builtin_amdgcn_fdot2)
#define FDOT2(a, b, c) __builtin_amdgcn_fdot2((a), (b), (c), false)
#else
__device__ __forceinline__ float fdot2_sw(h16x2 a, h16x2 b, float c) {
  return (float)a.x * (float)b.x + (float)a.y * (float)b.y + c;
}
#define FDOT2(a, b, c) fdot2_sw((a), (b), (c))
#endif

template <int NW>
__device__ __forceinline__ float blockSum(float v, float* sred) {
  int lane = threadIdx.x & 63, w = threadIdx.x >> 6;
#pragma unroll
  for (int o = 32; o; o >>= 1) v += __shfl_xor(v, o);
  __syncthreads();
  if (lane == 0) sred[w] = v;
  __syncthreads();
  float r = 0.f;
#pragma unroll
  for (int i = 0; i < NW; ++i) r += sred[i];
  return r;
}

// ---------- CSR build ----------
__global__ void k_hist(const int* __restrict__ dst, int* __restrict__ counts, int E) {
  int e = blockIdx.x * 256 + threadIdx.x;
  if (e < E) atomicAdd(&counts[dst[e]], 1);
}

__global__ __launch_bounds__(1024) void k_scan(const int* __restrict__ counts,
                                               int* __restrict__ offs, int n) {
  __shared__ int sd[1024];
  __shared__ int run;
  int tid = threadIdx.x;
  if (tid == 0) run = 0;
  __syncthreads();
  for (int base = 0; base < n; base += 1024) {
    int i = base + tid;
    int v = (i < n) ? counts[i] : 0;
    sd[tid] = v;
    __syncthreads();
    int acc = v;
    for (int off = 1; off < 1024; off <<= 1) {
      int t = (tid >= off) ? sd[tid - off] : 0;
      __syncthreads();
      acc += t;
      sd[tid] = acc;
      __syncthreads();
    }
    int r = run;
    if (i < n) offs[i] = r + acc - v;  // exclusive
    __syncthreads();
    if (tid == 1023) run = r + sd[1023];
    __syncthreads();
  }
  if (threadIdx.x == 0) offs[n] = run;
}

__global__ void k_scatter(const int* __restrict__ dst, const int* __restrict__ offs,
                          int* __restrict__ cursor, int* __restrict__ eidx, int E) {
  int e = blockIdx.x * 256 + threadIdx.x;
  if (e < E) {
    int d = dst[e];
    int p = offs[d] + atomicAdd(&cursor[d], 1);
    eidx[p] = e;
  }
}

__global__ void k_srcperm(const int* __restrict__ eidx, const int* __restrict__ srcArr,
                          int* __restrict__ srcs, int E) {
  int i = blockIdx.x * 256 + threadIdx.x;
  if (i < E) srcs[i] = srcArr[eidx[i]];
}

// eah[ii][kp] = half2(ea[eidx[ii]][2kp], ea[eidx[ii]][2kp+1]) ; CSR order
__global__ void k_eapermh(const int* __restrict__ eidx, const float* __restrict__ ea,
                          unsigned int* __restrict__ eah, int E) {
  int gid = blockIdx.x * 256 + threadIdx.x;
  if (gid < E * 8) {
    int ii = gid >> 3, kp = gid & 7;
    int e = eidx[ii];
    float v0 = ea[(size_t)e * 16 + 2 * kp];
    float v1 = ea[(size_t)e * 16 + 2 * kp + 1];
    eah[gid] = pk2u(v0, v1);
  }
}

// ---------- weight prepack: w4t[layer][c][k] bf16, c = tbl*256+j ----------
__global__ void k_pack(const float* __restrict__ conv_Wf, const float* __restrict__ conv_Ws,
                       unsigned short* __restrict__ w4t) {
  int layer = blockIdx.y;
  int gid = blockIdx.x * 256 + threadIdx.x;
  int k = gid & 255;
  int c = gid >> 8;  // 0..1023
  int j = c & 255;
  int tbl = c >> 8;
  const float* W = (tbl < 2) ? conv_Wf : conv_Ws;
  int krow = (tbl & 1) ? 256 + k : k;
  float v = W[((size_t)layer * 528 + krow) * 256 + j];
  w4t[((size_t)layer * 1024 + c) * 256 + k] = f2bf(v);
}

// edge-weight f16 prepack, PER-DIM layout: whd[layer][d][16]
// pr<8 -> f-gate k-pair pr ; pr>=8 -> s-gate k-pair pr-8
__global__ void k_packEd(const float* __restrict__ conv_Wf, const float* __restrict__ conv_Ws,
                         unsigned int* __restrict__ whd) {
  int layer = blockIdx.y;
  int gid = blockIdx.x * 256 + threadIdx.x;  // 256*16 = 4096 per layer
  int d = gid >> 4, pr = gid & 15;
  int g = pr >> 3, kp = pr & 7;
  const float* W = g ? conv_Ws : conv_Wf;
  float v0 = W[((size_t)layer * 528 + 512 + 2 * kp) * 256 + d];
  float v1 = W[((size_t)layer * 528 + 512 + 2 * kp + 1) * 256 + d];
  whd[((size_t)layer * 256 + d) * 16 + pr] = pk2u(v0, v1);
}

// ---------- GNN input layer ----------
__global__ void k_gin(const float* __restrict__ x, const float* __restrict__ W,
                      const float* __restrict__ bias, float* __restrict__ h,
                      unsigned short* __restrict__ hbf) {
  int n = blockIdx.x, j = threadIdx.x;
  float xv[7];
#pragma unroll
  for (int k = 0; k < 7; ++k) xv[k] = ntn_f(x[n * 7 + k], 3.f, -3.f);
  float acc = bias[j];
#pragma unroll
  for (int k = 0; k < 7; ++k) acc += xv[k] * W[k * 256 + j];
  float o = silu_f(acc);
  h[(size_t)n * 256 + j] = o;
  hbf[(size_t)n * 256 + j] = f2bf(o);
}

// ---------- MFMA node GEMM: P[N,1024](bf16) = hbf @ w4t^T (+bias on dst cols) ----------
__global__ __launch_bounds__(256) void k_gemm_bf16(
    const unsigned short* __restrict__ Abf,  // [M,256] bf16 row-major
    const unsigned short* __restrict__ w4t,  // [1024,256] bf16 (col, k)
    const float* __restrict__ bf, const float* __restrict__ bs,
    unsigned short* __restrict__ Pout) {     // [M,1024] bf16
  __shared__ unsigned short As[128 * 56];
  __shared__ unsigned short Bs[128 * 56];
  int tid = threadIdx.x;
  int lane = tid & 63, w = tid >> 6;
  int wr = w >> 1, wc = w & 1;
  int m0 = blockIdx.x * 128, n0 = blockIdx.y * 128;
  int l15 = lane & 15, l4 = lane >> 4;
  f32x4 acc[4][4];
#pragma unroll
  for (int i = 0; i < 4; ++i)
#pragma unroll
    for (int j = 0; j < 4; ++j) acc[i][j] = (f32x4)0.f;
  for (int kt = 0; kt < 8; ++kt) {
    int k0 = kt * 32;
    if (kt) __syncthreads();
#pragma unroll
    for (int c = 0; c < 2; ++c) {
      int chunk = tid + c * 256;
      int row = chunk >> 2, q = chunk & 3;
      *(uint4*)&As[row * 56 + q * 8] =
          *(const uint4*)&Abf[(size_t)(m0 + row) * 256 + k0 + q * 8];
      *(uint4*)&Bs[row * 56 + q * 8] =
          *(const uint4*)&w4t[(size_t)(n0 + row) * 256 + k0 + q * 8];
    }
    __syncthreads();
    short8 a[4], b[4];
#pragma unroll
    for (int f = 0; f < 4; ++f) {
      a[f] = *(const short8*)&As[(wr * 64 + f * 16 + l15) * 56 + l4 * 8];
      b[f] = *(const short8*)&Bs[(wc * 64 + f * 16 + l15) * 56 + l4 * 8];
    }
#pragma unroll
    for (int i = 0; i < 4; ++i)
#pragma unroll
      for (int j = 0; j < 4; ++j)
        acc[i][j] = __builtin_amdgcn_mfma_f32_16x16x32_bf16(a[i], b[j], acc[i][j], 0, 0, 0);
  }
#pragma unroll
  for (int j = 0; j < 4; ++j) {
    int gcol = n0 + wc * 64 + j * 16 + l15;
    float bias = (gcol < 256) ? bf[gcol] : (gcol >= 512 && gcol < 768) ? bs[gcol - 512] : 0.f;
#pragma unroll
    for (int i = 0; i < 4; ++i) {
#pragma unroll
      for (int r = 0; r < 4; ++r) {
        int grow = m0 + wr * 64 + i * 16 + l4 * 4 + r;
        Pout[(size_t)grow * 1024 + gcol] = f2bf(acc[i][j][r] + bias);
      }
    }
  }
}

// ---------- fused edge-message + aggregate + residual + LN ----------
// FOUR WAVES PER NODE; lane owns ONE dim d = wave*64 + lane. This is the
// r13/r14 config (empirical floor: 151us/layer, VALUBusy 94%, occ 79% across
// 7 residency/ISA variants) + isolated fast-sigmoid (r18).
__global__ __launch_bounds__(256) void k_edge4(
    const float* __restrict__ h, const unsigned short* __restrict__ P,
    const unsigned int* __restrict__ eah,
    const int* __restrict__ srcs, const int* __restrict__ offs,
    const unsigned int* __restrict__ whd,  // this layer: [256 d][16]
    const float* __restrict__ lng, const float* __restrict__ lnb,
    float* __restrict__ hout, unsigned short* __restrict__ hbfout) {
  __shared__ float sr1[4], sr2[4];
  int tid = threadIdx.x, lane = tid & 63, w = tid >> 6;
  int n = blockIdx.x;
  int d = w * 64 + lane;

  const uint4* wb = (const uint4*)(whd + (size_t)d * 16);
  uint4 wq0 = wb[0], wq1 = wb[1], wq2 = wb[2], wq3 = wb[3];

  float lg = lng[d], lb = lnb[d];
  const unsigned short* Pn = P + (size_t)n * 1024;
  float pfd = bfu(Pn[d]);        // dst f
  float psd = bfu(Pn[512 + d]);  // dst s
  float hn = h[(size_t)n * 256 + d];
  float acc = 0.f;
  int e0 = __builtin_amdgcn_readfirstlane(offs[n]);
  int e1 = __builtin_amdgcn_readfirstlane(offs[n + 1]);
  const unsigned short* Pf = P + 256 + d;  // gather base

  for (int ii = e0; ii < e1; ++ii) {
    int s = srcs[ii];  // uniform -> scalar load
    size_t so = (size_t)s * 1024;
    unsigned short uf = Pf[so];        // src f gather (128B/wave contiguous)
    unsigned short us = Pf[so + 512];  // src s gather
    const uint4* e4 = (const uint4*)(eah + (size_t)ii * 8);  // uniform
    uint4 ea0 = e4[0], ea1 = e4[1];
    float af = pfd, as_ = psd;
    af = FDOT2(u2h(wq0.x), u2h(ea0.x), af);
    af = FDOT2(u2h(wq0.y), u2h(ea0.y), af);
    af = FDOT2(u2h(wq0.z), u2h(ea0.z), af);
    af = FDOT2(u2h(wq0.w), u2h(ea0.w), af);
    af = FDOT2(u2h(wq1.x), u2h(ea1.x), af);
    af = FDOT2(u2h(wq1.y), u2h(ea1.y), af);
    af = FDOT2(u2h(wq1.z), u2h(ea1.z), af);
    af = FDOT2(u2h(wq1.w), u2h(ea1.w), af);
    as_ = FDOT2(u2h(wq2.x), u2h(ea0.x), as_);
    as_ = FDOT2(u2h(wq2.y), u2h(ea0.y), as_);
    as_ = FDOT2(u2h(wq2.z), u2h(ea0.z), as_);
    as_ = FDOT2(u2h(wq2.w), u2h(ea0.w), as_);
    as_ = FDOT2(u2h(wq3.x), u2h(ea1.x), as_);
    as_ = FDOT2(u2h(wq3.y), u2h(ea1.y), as_);
    as_ = FDOT2(u2h(wq3.z), u2h(ea1.z), as_);
    as_ = FDOT2(u2h(wq3.w), u2h(ea1.w), as_);
    af += bfu(uf);
    as_ += bfu(us);
    acc += sigmoid_fast(af) * softplus_f(as_);
  }
  float cv = hn + acc;
  float t = silu_f(cv) + hn;
  float s1 = t, s2 = t * t;
#pragma unroll
  for (int o = 32; o; o >>= 1) {
    s1 += __shfl_xor(s1, o);
    s2 += __shfl_xor(s2, o);
  }
  if (lane == 0) { sr1[w] = s1; sr2[w] = s2; }
  __syncthreads();
  float S1 = sr1[0] + sr1[1] + sr1[2] + sr1[3];
  float S2 = sr2[0] + sr2[1] + sr2[2] + sr2[3];
  float mean = S1 * (1.f / 256.f);
  float var = S2 * (1.f / 256.f) - mean * mean;
  float inv = rsqrtf(var + 1e-5f);
  float o0 = (t - mean) * inv * lg + lb;
  hout[(size_t)n * 256 + d] = o0;
  hbfout[(size_t)n * 256 + d] = f2bf(o0);
}

// ---------- pooling: batch = repeat(arange(256),100) -> contiguous segments ----------
__global__ __launch_bounds__(256) void k_pool2(const float* __restrict__ h,
                                               float* __restrict__ pooled) {
  int b = blockIdx.x, j = threadIdx.x;
  const float* hp = h + (size_t)b * 100 * 256 + j;
  float s = 0.f;
  for (int i = 0; i < 100; ++i) s += hp[(size_t)i * 256];
  pooled[b * 256 + j] = s * 0.01f;
}

__global__ void k_zgnn(const float* __restrict__ pooled,
                       const float* __restrict__ W, const float* __restrict__ bias,
                       float* __restrict__ zf) {
  int b = blockIdx.x, j = threadIdx.x;  // 192 threads
  float acc = bias[j];
  for (int k = 0; k < 256; ++k) acc += pooled[b * 256 + k] * W[k * 192 + j];
  zf[b * 384 + j] = ntn_def(acc);
}

// ---------- TDA projector ----------
__global__ __launch_bounds__(256) void k_tda(const float* __restrict__ tda,
    const float* __restrict__ W1, const float* __restrict__ b1,
    const float* __restrict__ g1, const float* __restrict__ bb1,
    const float* __restrict__ W2, const float* __restrict__ b2,
    const float* __restrict__ g2, const float* __restrict__ bb2,
    const float* __restrict__ W3, const float* __restrict__ b3, float* __restrict__ zf) {
  __shared__ float sin_[32];
  __shared__ float sa[256];
  __shared__ float sred[4];
  int b = blockIdx.x, tid = threadIdx.x;
  if (tid < 32) sin_[tid] = ntn_f(tda[b * 32 + tid], 3.f, -3.f);
  __syncthreads();
  float v = b1[tid];
#pragma unroll
  for (int k = 0; k < 32; ++k) v += sin_[k] * W1[k * 256 + tid];
  v = silu_f(v);
  float s1 = blockSum<4>(v, sred);
  float s2 = blockSum<4>(v * v, sred);
  float mean = s1 * (1.f / 256.f), var = s2 * (1.f / 256.f) - mean * mean;
  float inv = rsqrtf(var + 1e-5f);
  v = (v - mean) * inv * g1[tid] + bb1[tid];
  sa[tid] = v;
  __syncthreads();
  float v2 = b2[tid];
  for (int k = 0; k < 256; ++k) v2 += sa[k] * W2[k * 256 + tid];
  v2 = silu_f(v2);
  s1 = blockSum<4>(v2, sred);
  s2 = blockSum<4>(v2 * v2, sred);
  mean = s1 * (1.f / 256.f); var = s2 * (1.f / 256.f) - mean * mean;
  inv = rsqrtf(var + 1e-5f);
  v2 = (v2 - mean) * inv * g2[tid] + bb2[tid];
  __syncthreads();
  sa[tid] = v2;
  __syncthreads();
  if (tid < 128) {
    float o = b3[tid];
    for (int k = 0; k < 256; ++k) o += sa[k] * W3[k * 128 + tid];
    zf[b * 384 + 192 + tid] = ntn_def(o);
  }
}

// ---------- MEGNet projector ----------
__global__ __launch_bounds__(128) void k_meg(const float* __restrict__ mg,
    const float* __restrict__ W1, const float* __restrict__ b1,
    const float* __restrict__ g1, const float* __restrict__ bb1,
    const float* __restrict__ W2, const float* __restrict__ b2,
    const float* __restrict__ g2, const float* __restrict__ bb2,
    const float* __restrict__ W3, const float* __restrict__ b3, float* __restrict__ zf) {
  __shared__ float sin_[16];
  __shared__ float sa[128];
  __shared__ float sred[2];
  int b = blockIdx.x, tid = threadIdx.x;
  if (tid < 16) sin_[tid] = ntn_f(mg[b * 16 + tid], 3.f, -3.f);
  __syncthreads();
  float v = b1[tid];
#pragma unroll
  for (int k = 0; k < 16; ++k) v += sin_[k] * W1[k * 128 + tid];
  v = silu_f(v);
  float s1 = blockSum<2>(v, sred);
  float s2 = blockSum<2>(v * v, sred);
  float mean = s1 * (1.f / 128.f), var = s2 * (1.f / 128.f) - mean * mean;
  float inv = rsqrtf(var + 1e-5f);
  v = (v - mean) * inv * g1[tid] + bb1[tid];
  sa[tid] = v;
  __syncthreads();
  float v2 = b2[tid];
  for (int k = 0; k < 128; ++k) v2 += sa[k] * W2[k * 128 + tid];
  v2 = silu_f(v2);
  s1 = blockSum<2>(v2, sred);
  s2 = blockSum<2>(v2 * v2, sred);
  mean = s1 * (1.f / 128.f); var = s2 * (1.f / 128.f) - mean * mean;
  inv = rsqrtf(var + 1e-5f);
  v2 = (v2 - mean) * inv * g2[tid] + bb2[tid];
  __syncthreads();
  sa[tid] = v2;
  __syncthreads();
  if (tid < 64) {
    float o = b3[tid];
    for (int k = 0; k < 128; ++k) o += sa[k] * W3[k * 64 + tid];
    zf[b * 384 + 320 + tid] = ntn_def(o);
  }
}

// ---------- fused fusion-LN + CPPN head (fully parallel) ----------
__global__ __launch_bounds__(384) void k_cppn(const float* __restrict__ zf,
    const float* __restrict__ flng, const float* __restrict__ flnb,
    const float* __restrict__ g1W, const float* __restrict__ g1b,
    const float* __restrict__ hg, const float* __restrict__ hb,
    const float* __restrict__ g2W, const float* __restrict__ g2b,
    const float* __restrict__ g3W, const float* __restrict__ g3b,
    const float* __restrict__ plW, const float* __restrict__ plb,
    const float* __restrict__ pq1W, const float* __restrict__ pq1b,
    const float* __restrict__ pq2W, const float* __restrict__ pq2b,
    const float* __restrict__ pc1W, const float* __restrict__ pc1b,
    const float* __restrict__ pc2W, const float* __restrict__ pc2b,
    float* __restrict__ zout, float* __restrict__ y) {
  __shared__ float sz[384];
  __shared__ float sred[6];
  __shared__ float sg[48];
  __shared__ float s24[24];
  __shared__ float gates[6];
  __shared__ float lin[6];
  __shared__ float qv[6], cvv[6];
  __shared__ float mn48, iv48;
  __shared__ float prodq[1152];  // 6*192
  __shared__ float prodc[576];   // 6*96
  int b = blockIdx.x, tid = threadIdx.x;
  int lane = tid & 63, wv = tid >> 6;

  float v = zf[(size_t)b * 384 + tid];
  float s1 = blockSum<6>(v, sred);
  float s2 = blockSum<6>(v * v, sred);
  float mean = s1 * (1.f / 384.f), var = s2 * (1.f / 384.f) - mean * mean;
  float inv = rsqrtf(var + 1e-5f);
  float zv = (v - mean) * inv * flng[tid] + flnb[tid];
  sz[tid] = zv;
  zout[(size_t)b * 384 + tid] = zv;
  __syncthreads();

  {
    int j = tid >> 3, p = tid & 7;
    float a = 0.f;
    for (int d = p; d < 384; d += 8) a += sz[d] * g1W[d * 48 + j];
    a += __shfl_xor(a, 1);
    a += __shfl_xor(a, 2);
    a += __shfl_xor(a, 4);
    if (p == 0) sg[j] = silu_f(a + g1b[j]);
  }
  __syncthreads();
  if (tid < 64) {
    float x = (tid < 48) ? sg[tid] : 0.f;
    float t1 = x, t2 = x * x;
#pragma unroll
    for (int o = 32; o; o >>= 1) {
      t1 += __shfl_xor(t1, o);
      t2 += __shfl_xor(t2, o);
    }
    if (tid == 0) {
      mn48 = t1 * (1.f / 48.f);
      float vr = t2 * (1.f / 48.f) - mn48 * mn48;
      iv48 = rsqrtf(vr + 1e-5f);
    }
  }
  __syncthreads();
  if (tid < 48) sg[tid] = (sg[tid] - mn48) * iv48 * hg[tid] + hb[tid];
  __syncthreads();
  {
    int j = tid >> 4, p = tid & 15;
    int d0 = p * 3;
    float a = sg[d0] * g2W[d0 * 24 + j] + sg[d0 + 1] * g2W[(d0 + 1) * 24 + j] +
              sg[d0 + 2] * g2W[(d0 + 2) * 24 + j];
    a += __shfl_xor(a, 1);
    a += __shfl_xor(a, 2);
    a += __shfl_xor(a, 4);
    a += __shfl_xor(a, 8);
    if (p == 0) s24[j] = silu_f(a + g2b[j]);
  }
  __syncthreads();
  if (tid < 6) {
    float a = g3b[tid];
    for (int k = 0; k < 24; ++k) a += s24[k] * g3W[k * 6 + tid];
    gates[tid] = a;
  }
  __syncthreads();
  if (tid == 0) {
    float mx = gates[0];
    for (int i = 1; i < 6; ++i) mx = fmaxf(mx, gates[i]);
    float s = 0.f;
    for (int i = 0; i < 6; ++i) { gates[i] = __expf(gates[i] - mx); s += gates[i]; }
    float rs = 1.f / s;
    for (int i = 0; i < 6; ++i) gates[i] *= rs;
  }
  {
    float p = 0.f;
    for (int d = lane; d < 384; d += 64) p += sz[d] * plW[wv * 384 + d];
#pragma unroll
    for (int o = 32; o; o >>= 1) p += __shfl_xor(p, o);
    if (lane == 0) lin[wv] = p + plb[wv];
  }
  if (tid < 288) {
    int k = tid / 48, m4 = (tid % 48) * 4;
    f32x4 a = (f32x4)0.f;
    const float* Wp = pq1W + (size_t)k * 384 * 192 + m4;
    for (int d = 0; d < 384; ++d) {
      float4 w4 = *(const float4*)(Wp + (size_t)d * 192);
      float zd = sz[d];
      a.x += zd * w4.x; a.y += zd * w4.y; a.z += zd * w4.z; a.w += zd * w4.w;
    }
#pragma unroll
    for (int r = 0; r < 4; ++r) {
      int m = m4 + r;
      prodq[k * 192 + m] = silu_f(a[r] + pq1b[k * 192 + m]) * pq2W[k * 192 + m];
    }
  }
  if (tid < 144) {
    int k = tid / 24, m4 = (tid % 24) * 4;
    f32x4 a = (f32x4)0.f;
    const float* Wp = pc1W + (size_t)k * 384 * 96 + m4;
    for (int d = 0; d < 384; ++d) {
      float4 w4 = *(const float4*)(Wp + (size_t)d * 96);
      float zd = sz[d];
      a.x += zd * w4.x; a.y += zd * w4.y; a.z += zd * w4.z; a.w += zd * w4.w;
    }
#pragma unroll
    for (int r = 0; r < 4; ++r) {
      int m = m4 + r;
      float sl = silu_f(a[r] + pc1b[k * 96 + m]);
      prodc[k * 96 + m] = sl * sl * pc2W[k * 96 + m];
    }
  }
  __syncthreads();
  {
    float s = prodq[wv * 192 + lane] + prodq[wv * 192 + 64 + lane] +
              prodq[wv * 192 + 128 + lane];
#pragma unroll
    for (int o = 32; o; o >>= 1) s += __shfl_xor(s, o);
    if (lane == 0) qv[wv] = s + pq2b[wv];
    float c = prodc[wv * 96 + lane];
    float c2 = (lane < 32) ? prodc[wv * 96 + 64 + lane] : 0.f;
    float sc = c + c2;
#pragma unroll
    for (int o = 32; o; o >>= 1) sc += __shfl_xor(sc, o);
    if (lane == 0) cvv[wv] = sc + pc2b[wv];
  }
  __syncthreads();
  if (tid == 0) {
    float yy = 0.f;
    for (int k = 0; k < 6; ++k) yy += gates[k] * (lin[k] + qv[k] + cvv[k]);
    y[b] = yy;
  }
}

extern "C" void kernel_launch(void* const* d_in, const int* in_sizes, int n_in,
                              void* d_out, int out_size, void* d_ws, size_t ws_size,
                              hipStream_t stream) {
  const float* x         = (const float*)d_in[0];
  const float* edge_attr = (const float*)d_in[1];
  const float* tda       = (const float*)d_in[2];
  const float* megnet    = (const float*)d_in[3];
  const int*   edge_index= (const int*)d_in[4];
  const float* gin_W = (const float*)d_in[6];
  const float* gin_b = (const float*)d_in[7];
  const float* conv_Wf = (const float*)d_in[8];
  const float* conv_bf = (const float*)d_in[9];
  const float* conv_Ws = (const float*)d_in[10];
  const float* conv_bs = (const float*)d_in[11];
  const float* gln_g = (const float*)d_in[12];
  const float* gln_b = (const float*)d_in[13];
  const float* gout_W = (const float*)d_in[14];
  const float* gout_b = (const float*)d_in[15];
  const float* t1_W = (const float*)d_in[16];
  const float* t1_b = (const float*)d_in[17];
  const float* tln1_g = (const float*)d_in[18];
  const float* tln1_b = (const float*)d_in[19];
  const float* t2_W = (const float*)d_in[20];
  const float* t2_b = (const float*)d_in[21];
  const float* tln2_g = (const float*)d_in[22];
  const float* tln2_b = (const float*)d_in[23];
  const float* t3_W = (const float*)d_in[24];
  const float* t3_b = (const float*)d_in[25];
  const float* m1_W = (const float*)d_in[26];
  const float* m1_b = (const float*)d_in[27];
  const float* mln1_g = (const float*)d_in[28];
  const float* mln1_b = (const float*)d_in[29];
  const float* m2_W = (const float*)d_in[30];
  const float* m2_b = (const float*)d_in[31];
  const float* mln2_g = (const float*)d_in[32];
  const float* mln2_b = (const float*)d_in[33];
  const float* m3_W = (const float*)d_in[34];
  const float* m3_b = (const float*)d_in[35];
  const float* fln_g = (const float*)d_in[36];
  const float* fln_b = (const float*)d_in[37];
  const float* g1_W = (const float*)d_in[38];
  const float* g1_b = (const float*)d_in[39];
  const float* hln_g = (const float*)d_in[40];
  const float* hln_b = (const float*)d_in[41];
  const float* g2_W = (const float*)d_in[42];
  const float* g2_b = (const float*)d_in[43];
  const float* g3_W = (const float*)d_in[44];
  const float* g3_b = (const float*)d_in[45];
  const float* plin_W = (const float*)d_in[46];
  const float* plin_b = (const float*)d_in[47];
  const float* pq1_W = (const float*)d_in[48];
  const float* pq1_b = (const float*)d_in[49];
  const float* pq2_W = (const float*)d_in[50];
  const float* pq2_b = (const float*)d_in[51];
  const float* pc1_W = (const float*)d_in[52];
  const float* pc1_b = (const float*)d_in[53];
  const float* pc2_W = (const float*)d_in[54];
  const float* pc2_b = (const float*)d_in[55];

  // ---- workspace layout (~147 MB) ----
  float* ws = (float*)d_ws;
  float* hA = ws;                                        // NN*256 f32
  float* hB = hA + (size_t)NN * 256;
  float* pooled = hB + (size_t)NN * 256;                 // NB*256
  float* zf = pooled + (size_t)NB * 256;                 // NB*384
  unsigned short* hbfA = (unsigned short*)(zf + (size_t)NB * 384);  // NN*256 bf16
  unsigned short* hbfB = hbfA + (size_t)NN * 256;
  unsigned short* Pbf = hbfB + (size_t)NN * 256;         // NN*1024 bf16
  unsigned short* w4t = Pbf + (size_t)NN * 1024;         // 6*1024*256 bf16
  unsigned int* whd6 = (unsigned int*)(w4t + (size_t)6 * 1024 * 256);  // 6*256*16 uint
  unsigned int* eah = whd6 + (size_t)6 * 256 * 16;       // NE*8 uint (f16 pairs)
  int* counts = (int*)(eah + (size_t)NE * 8);            // NN
  int* cursor = counts + NN;                             // NN
  int* offs = cursor + NN;                               // NN+1
  int* eidx = offs + NN + 1;                             // NE
  int* srcs = eidx + NE;                                 // NE

  const int* srcArr = edge_index;       // row 0 = src
  const int* dstArr = edge_index + NE;  // row 1 = dst

  hipMemsetAsync(counts, 0, (size_t)2 * NN * sizeof(int), stream);

  k_hist<<<(NE + 255) / 256, 256, 0, stream>>>(dstArr, counts, NE);
  k_scan<<<1, 1024, 0, stream>>>(counts, offs, NN);
  k_scatter<<<(NE + 255) / 256, 256, 0, stream>>>(dstArr, offs, cursor, eidx, NE);
  k_srcperm<<<(NE + 255) / 256, 256, 0, stream>>>(eidx, srcArr, srcs, NE);
  k_eapermh<<<(NE * 8 + 255) / 256, 256, 0, stream>>>(eidx, edge_attr, eah, NE);
  k_pack<<<dim3(1024, 6), 256, 0, stream>>>(conv_Wf, conv_Ws, w4t);
  k_packEd<<<dim3(16, 6), 256, 0, stream>>>(conv_Wf, conv_Ws, whd6);

  k_gin<<<NN, 256, 0, stream>>>(x, gin_W, gin_b, hA, hbfA);

  float* hcur = hA;          float* hnext = hB;
  unsigned short* bcur = hbfA; unsigned short* bnext = hbfB;
  for (int i = 0; i < 6; ++i) {
    k_gemm_bf16<<<dim3(NN / 128, 8), 256, 0, stream>>>(
        bcur, w4t + (size_t)i * 1024 * 256, conv_bf + i * 256, conv_bs + i * 256, Pbf);
    k_edge4<<<NN, 256, 0, stream>>>(hcur, Pbf, eah, srcs, offs,
                                    whd6 + (size_t)i * 256 * 16,
                                    gln_g + i * 256, gln_b + i * 256, hnext, bnext);
    float* tf = hcur; hcur = hnext; hnext = tf;
    unsigned short* tb = bcur; bcur = bnext; bnext = tb;
  }

  k_pool2<<<NB, 256, 0, stream>>>(hcur, pooled);
  k_zgnn<<<NB, 192, 0, stream>>>(pooled, gout_W, gout_b, zf);
  k_tda<<<NB, 256, 0, stream>>>(tda, t1_W, t1_b, tln1_g, tln1_b, t2_W, t2_b, tln2_g, tln2_b,
                                t3_W, t3_b, zf);
  k_meg<<<NB, 128, 0, stream>>>(megnet, m1_W, m1_b, mln1_g, mln1_b, m2_W, m2_b, mln2_g, mln2_b,
                                m3_W, m3_b, zf);

  float* yout = (float*)d_out;
  float* zout = yout + NB;
  k_cppn<<<NB, 384, 0, stream>>>(zf, fln_g, fln_b,
                                 g1_W, g1_b, hln_g, hln_b, g2_W, g2_b, g3_W, g3_b,
                                 plin_W, plin_b, pq1_W, pq1_b, pq2_W, pq2_b,
                                 pc1_W, pc1_b, pc2_W, pc2_b, zout, yout);
}